// Round 1
// baseline (59020.209 us; speedup 1.0000x reference)
//
#include <hip/hip_runtime.h>
#include <math.h>

// Problem constants
#define T_ 512
#define B_ 128
#define I_ 512
#define H_ 1024

typedef __attribute__((ext_vector_type(8))) short short8;   // 8 x bf16 (4 VGPRs)
typedef __attribute__((ext_vector_type(4))) float floatx4;  // MFMA accumulator

// ---- f32 <-> bf16 split helpers (RNE via integer trick; no NaN in this data) ----
__device__ inline unsigned int f32_to_bf16_rne(float v) {
    unsigned int b = __builtin_bit_cast(unsigned int, v);
    b += 0x7FFFu + ((b >> 16) & 1u);
    return b >> 16;
}
__device__ inline float bf16_to_f32(unsigned int s) {
    unsigned int b = s << 16;
    return __builtin_bit_cast(float, b);
}
// split one f32 into hi+lo bf16 (combined ~16-bit mantissa)
__device__ inline void split1(float v, short& hi, short& lo) {
    unsigned int h = f32_to_bf16_rne(v);
    float r = v - bf16_to_f32(h);
    unsigned int l = f32_to_bf16_rne(r);
    hi = (short)h;
    lo = (short)l;
}

// ---------------- weight split-transpose: f32 [K,N] -> bf16 hi/lo [N,K] ----------------
__global__ void transpose_split_kernel(const float* __restrict__ in, const float* __restrict__ in2,
                                       short* __restrict__ outT_hi, short* __restrict__ outT_lo,
                                       int K, int N) {
    int total = K * N;
    int idx = blockIdx.x * blockDim.x + threadIdx.x;
    int stride = gridDim.x * blockDim.x;
    for (int i = idx; i < total; i += stride) {
        int n = i / K;
        int k = i - n * K;
        float v = in[(size_t)k * N + n];
        if (in2) v += in2[(size_t)k * N + n];
        short h, l;
        split1(v, h, l);
        outT_hi[i] = h;
        outT_lo[i] = l;
    }
}

// ---------------- split GEMM: C[M,N=1024] (=|+=) A[M,K](f32) x BT[N,K](bf16 hi/lo) ----------------
// In-register split of A into hi/lo; 3 MFMAs per 32-wide K-chunk (Ah*Bh + Al*Bh + Ah*Bl).
// Block: 256 threads = 4 waves stacked along M (block tile 64 x 16).
// grid.x = M/64, grid.y = 1024/16. If avg_off > 0, A-value = 0.5*(A[i] + A[i+avg_off]).
__global__ __launch_bounds__(256) void gemm_split_kernel(const float* __restrict__ A,
                                                         const short* __restrict__ BT_hi,
                                                         const short* __restrict__ BT_lo,
                                                         float* __restrict__ C,
                                                         int K, int avg_off, int accumulate) {
    int tid = threadIdx.x;
    int wave = tid >> 6;
    int lane = tid & 63;
    int mbase = blockIdx.x * 64 + wave * 16;
    int nbase = blockIdx.y * 16;

    int arow = mbase + (lane & 15);
    int brow = nbase + (lane & 15);
    int koff = (lane >> 4) * 8;

    const float* ap = A + (size_t)arow * K + koff;
    const short* bph = BT_hi + (size_t)brow * K + koff;
    const short* bpl = BT_lo + (size_t)brow * K + koff;

    floatx4 acc = {0.f, 0.f, 0.f, 0.f};
    for (int k = 0; k < K; k += 32) {
        short8 ah, al, bh, bl;
        bh = *(const short8*)(bph + k);
        bl = *(const short8*)(bpl + k);
        #pragma unroll
        for (int j = 0; j < 8; ++j) {
            float v = ap[k + j];
            if (avg_off) v = 0.5f * (v + ap[k + j + avg_off]);
            short h, l;
            split1(v, h, l);
            ah[j] = h;
            al[j] = l;
        }
        acc = __builtin_amdgcn_mfma_f32_16x16x32_bf16(ah, bh, acc, 0, 0, 0);
        acc = __builtin_amdgcn_mfma_f32_16x16x32_bf16(al, bh, acc, 0, 0, 0);
        acc = __builtin_amdgcn_mfma_f32_16x16x32_bf16(ah, bl, acc, 0, 0, 0);
    }

    int rbase = mbase + ((lane >> 4) << 2);
    int c = nbase + (lane & 15);
    #pragma unroll
    for (int r = 0; r < 4; ++r) {
        size_t idx = (size_t)(rbase + r) * H_ + c;
        if (accumulate) C[idx] += acc[r];
        else            C[idx] = acc[r];
    }
}

// ---------------- persistent recurrence: out[t] = tanh(pre[t] + out[t-1] @ Wh) ----------------
// Grid: 512 blocks of 256 threads (4 waves). Block (mb, nb) owns output tile
// [mb*16 .. mb*16+16) x [nb*16 .. nb*16+16); K=1024 split across the 4 waves (256 each).
// mb = blockIdx.x & 7 so each of the 8 independent batch-row chains maps onto one XCD
// (round-robin dispatch). Wh tile (16 x 1024, hi+lo) lives in LDS for all steps.
// h state is kept as split bf16 hi/lo in a 2-deep ping-pong; f32 goes straight to outf.
// Sync: per-(group, step) arrival counter; a block at step t waits until all 64 blocks of
// its group have published h[t-1]. Device-scope atomics + threadfence per XCD-coherence rules.
// Co-residency: 512 blocks x 70.1 KB LDS = exactly 2 blocks/CU on 256 CUs -> no deadlock.
#define GRP_NB 64

__global__ __launch_bounds__(256) void recur_kernel(const short* __restrict__ WhT_hi,
                                                    const short* __restrict__ WhT_lo,
                                                    const float* __restrict__ pre,
                                                    float* __restrict__ outf,
                                                    short* __restrict__ h_hi,
                                                    short* __restrict__ h_lo,
                                                    unsigned int* __restrict__ cnt,
                                                    int nsteps) {
    // +8 shorts pad: row stride 2064 B -> ds_read_b128 rows land 4 banks apart (2-way = free)
    __shared__ short bh_lds[16][1032];
    __shared__ short bl_lds[16][1032];
    __shared__ float red[4][256];

    const int tid = threadIdx.x;
    const int wave = tid >> 6;
    const int lane = tid & 63;
    const int mb = blockIdx.x & 7;   // batch-row group == XCD (round-robin dispatch)
    const int nb = blockIdx.x >> 3;  // 0..63
    const int mbase = mb * 16;
    const int nbase = nb * 16;
    const size_t BH = (size_t)B_ * H_;

    // preload this block's weight tile into LDS (once, reused for all steps)
    for (int i = tid; i < 2048; i += 256) {
        int n = i >> 7;              // 0..15
        int k8 = (i & 127) << 3;     // 0..1016 step 8
        *(short8*)&bh_lds[n][k8] = *(const short8*)(WhT_hi + (size_t)(nbase + n) * H_ + k8);
        *(short8*)&bl_lds[n][k8] = *(const short8*)(WhT_lo + (size_t)(nbase + n) * H_ + k8);
    }
    __syncthreads();

    const int arow = mbase + (lane & 15);
    const int brow = lane & 15;
    const int koff = wave * 256 + ((lane >> 4) << 3);

    // epilogue indices (wave 0 only)
    const int erow = mbase + ((lane >> 4) << 2);
    const int ecol = nbase + (lane & 15);

    unsigned int* cg = cnt + mb * T_;

    for (int t = 0; t < nsteps; ++t) {
        // prefetch pre[t] tile: independent of the recurrence, issue before the spin
        float pv[4];
        if (tid < 64) {
            #pragma unroll
            for (int r = 0; r < 4; ++r)
                pv[r] = pre[(size_t)t * BH + (size_t)(erow + r) * H_ + ecol];
        }

        floatx4 acc = {0.f, 0.f, 0.f, 0.f};
        if (t > 0) {
            if (tid == 0) {
                while (__hip_atomic_load(&cg[t - 1], __ATOMIC_ACQUIRE,
                                         __HIP_MEMORY_SCOPE_AGENT) < GRP_NB)
                    __builtin_amdgcn_s_sleep(1);
            }
            __syncthreads();

            const size_t hoff = ((t - 1) & 1) ? BH : 0;
            const short* aph = h_hi + hoff + (size_t)arow * H_ + koff;
            const short* apl = h_lo + hoff + (size_t)arow * H_ + koff;
            #pragma unroll
            for (int k = 0; k < 256; k += 32) {
                short8 ah = *(const short8*)(aph + k);
                short8 al = *(const short8*)(apl + k);
                short8 bh = *(const short8*)&bh_lds[brow][koff + k];
                short8 bl = *(const short8*)&bl_lds[brow][koff + k];
                acc = __builtin_amdgcn_mfma_f32_16x16x32_bf16(ah, bh, acc, 0, 0, 0);
                acc = __builtin_amdgcn_mfma_f32_16x16x32_bf16(al, bh, acc, 0, 0, 0);
                acc = __builtin_amdgcn_mfma_f32_16x16x32_bf16(ah, bl, acc, 0, 0, 0);
            }
        }

        #pragma unroll
        for (int r = 0; r < 4; ++r)
            red[wave][r * 64 + lane] = acc[r];   // lane-stride-1: conflict-free
        __syncthreads();

        if (tid < 64) {  // wave 0: reduce, tanh, publish f32 + split bf16 state
            const size_t hoff = (t & 1) ? BH : 0;
            #pragma unroll
            for (int r = 0; r < 4; ++r) {
                float s = red[0][r * 64 + lane] + red[1][r * 64 + lane]
                        + red[2][r * 64 + lane] + red[3][r * 64 + lane];
                float v = tanhf(pv[r] + s);
                size_t idx = (size_t)(erow + r) * H_ + ecol;
                outf[(size_t)t * BH + idx] = v;
                short hh, ll;
                split1(v, hh, ll);
                h_hi[hoff + idx] = hh;
                h_lo[hoff + idx] = ll;
            }
            __threadfence();  // device-scope release of h/out stores (per-XCD L2 rules)
        }
        __syncthreads();  // also protects red[] for next iteration
        if (tid == 0)
            __hip_atomic_fetch_add(&cg[t], 1u, __ATOMIC_RELEASE, __HIP_MEMORY_SCOPE_AGENT);
    }
}

// ---------------- launcher ----------------

extern "C" void kernel_launch(void* const* d_in, const int* in_sizes, int n_in,
                              void* d_out, int out_size, void* d_ws, size_t ws_size,
                              hipStream_t stream) {
    const float* x   = (const float*)d_in[0];
    const float* Wi0 = (const float*)d_in[1];
    const float* Wh0 = (const float*)d_in[2];
    const float* Ws0 = (const float*)d_in[3];
    const float* Wi1 = (const float*)d_in[4];
    const float* Wh1 = (const float*)d_in[5];
    const float* Ws1 = (const float*)d_in[6];
    float* out = (float*)d_out;
    char* ws = (char*)d_ws;

    const size_t BH = (size_t)B_ * H_;        // 131072
    const size_t OUT1_OFF = (size_t)T_ * BH;  // start of out1 in d_out

    // workspace layout (bytes); total ~273.1 MiB
    const size_t MB = 1048576ull;
    float* pre      = (float*)(ws + 0);                  // 512*128*1024 f32 = 256 MiB
    short* W0sumT_h = (short*)(ws + 256 * MB);           // 1024x512  = 1 MiB
    short* W0sumT_l = (short*)(ws + 257 * MB);
    short* Wh0T_h   = (short*)(ws + 258 * MB);           // 1024x1024 = 2 MiB
    short* Wh0T_l   = (short*)(ws + 260 * MB);
    short* Wi1T_h   = (short*)(ws + 262 * MB);
    short* Wi1T_l   = (short*)(ws + 264 * MB);
    short* Wh1T_h   = (short*)(ws + 266 * MB);
    short* Wh1T_l   = (short*)(ws + 268 * MB);
    short* Ws1T_h   = (short*)(ws + 270 * MB);           // 1024x512 = 1 MiB
    short* Ws1T_l   = (short*)(ws + 271 * MB);
    short* h_hi     = (short*)(ws + 272 * MB);           // 2 x B*H bf16 ping-pong = 512 KiB
    short* h_lo     = (short*)(ws + 272 * MB + 524288);  // 512 KiB
    unsigned int* cnt = (unsigned int*)(ws + 273 * MB);  // 8*512 u32 = 16 KiB

    // 1. split-transposed weights
    transpose_split_kernel<<<dim3((I_ * H_ + 255) / 256), 256, 0, stream>>>(Wi0, Ws0, W0sumT_h, W0sumT_l, I_, H_);
    transpose_split_kernel<<<dim3((H_ * H_ + 255) / 256), 256, 0, stream>>>(Wh0, nullptr, Wh0T_h, Wh0T_l, H_, H_);
    transpose_split_kernel<<<dim3((H_ * H_ + 255) / 256), 256, 0, stream>>>(Wi1, nullptr, Wi1T_h, Wi1T_l, H_, H_);
    transpose_split_kernel<<<dim3((H_ * H_ + 255) / 256), 256, 0, stream>>>(Wh1, nullptr, Wh1T_h, Wh1T_l, H_, H_);
    transpose_split_kernel<<<dim3((I_ * H_ + 255) / 256), 256, 0, stream>>>(Ws1, nullptr, Ws1T_h, Ws1T_l, I_, H_);

    // 2. pre0 = x @ (Wi0+Ws0) : M = 65536, K = 512
    gemm_split_kernel<<<dim3(65536 / 64, H_ / 16), 256, 0, stream>>>(
        x, W0sumT_h, W0sumT_l, pre, I_, 0, 0);

    // 3. layer-0 recurrence: one persistent kernel, 512 steps internally
    hipMemsetAsync(cnt, 0, 8 * T_ * sizeof(unsigned int), stream);
    recur_kernel<<<dim3(512), 256, 0, stream>>>(
        Wh0T_h, Wh0T_l, pre, out, h_hi, h_lo, cnt, T_);

    // 4. pre1 = out0[1:] @ Wi1 + sx1 @ Ws1 : M = 511*128 = 65408
    gemm_split_kernel<<<dim3(65408 / 64, H_ / 16), 256, 0, stream>>>(
        out + BH, Wi1T_h, Wi1T_l, pre, H_, 0, 0);
    gemm_split_kernel<<<dim3(65408 / 64, H_ / 16), 256, 0, stream>>>(
        x, Ws1T_h, Ws1T_l, pre, I_, B_ * I_, 1);

    // 5. layer-1 recurrence: 511 steps
    hipMemsetAsync(cnt, 0, 8 * T_ * sizeof(unsigned int), stream);
    recur_kernel<<<dim3(512), 256, 0, stream>>>(
        Wh1T_h, Wh1T_l, pre, out + OUT1_OFF, h_hi, h_lo, cnt, T_ - 1);
}